// Round 23
// baseline (183.114 us; speedup 1.0000x reference)
//
#include <hip/hip_runtime.h>
#include <hip/hip_bf16.h>

typedef _Float16 half8 __attribute__((ext_vector_type(8)));
typedef _Float16 half4 __attribute__((ext_vector_type(4)));
typedef _Float16 half2v __attribute__((ext_vector_type(2)));
typedef float f32x4 __attribute__((ext_vector_type(4)));

namespace {

constexpr int INW  = 87;
constexpr int ROWS = 128;   // rows per block (2 row-groups x 64)
constexpr int NT   = 1024;  // 16 waves: 2 row-groups x 8 col-stripes
constexpr int NSLICES = 76; // 3(WE) + 1(WD) + 64(heads) + 8(fc3)

// ws halves layout:
//   X_WE  [256][96]  n-major folded enc (k<77 real, k==77 bias row)
//   X_WD  [256][32]  n-major folded dec (k<10 real, k==10 bias row)
//   Y     fragment-major: slice i (76) x stripe w (8) x {qa,qb} x lane(64) x 8 halves
constexpr long O_WE = 0;        // 24576 halves
constexpr long O_WD = 24576;    // 8192 halves
constexpr long O_Y  = 32768;    // 76*8192 = 622592 halves

__device__ __forceinline__ int aidx(int row, int col) {
  return row * 256 + ((((col >> 3) ^ (row & 7)) << 3) | (col & 7));
}

// ---------------- prep: fold enc chain -> X_WE ----------------
__global__ __launch_bounds__(256)
void prep_fold_enc(const float* __restrict__ Wfc1, const float* __restrict__ bfc1,
                   const float* __restrict__ Wenc, const float* __restrict__ benc,
                   _Float16* __restrict__ ws)
{
  const int t = (int)blockIdx.x * 256 + (int)threadIdx.x;   // 96*256 threads
  const int n = t & 255, k = t >> 8;                        // k 0..95
  float acc = 0.f;
  if (k < 77) {
    for (int m = 0; m < 256; ++m) acc += Wfc1[(size_t)k * 256 + m] * Wenc[(size_t)m * 256 + n];
  } else if (k == 77) {
    for (int m = 0; m < 256; ++m) acc += bfc1[m] * Wenc[(size_t)m * 256 + n];
    acc += benc[n];
  }
  ws[O_WE + (long)n * 96 + k] = (_Float16)acc;
}

// ---------------- prep: fold dec chain -> X_WD ----------------
__global__ __launch_bounds__(256)
void prep_fold_dec(const float* __restrict__ Wfc2, const float* __restrict__ bfc2,
                   const float* __restrict__ Wdec, const float* __restrict__ bdec,
                   _Float16* __restrict__ ws)
{
  const int t = (int)blockIdx.x * 256 + (int)threadIdx.x;   // 32*256 threads
  const int n = t & 255, k = t >> 8;                        // k 0..31
  float acc = 0.f;
  if (k < 10) {
    for (int m = 0; m < 256; ++m) acc += Wfc2[(size_t)k * 256 + m] * Wdec[(size_t)m * 256 + n];
  } else if (k == 10) {
    for (int m = 0; m < 256; ++m) acc += bfc2[m] * Wdec[(size_t)m * 256 + n];
    acc += bdec[n];
  }
  ws[O_WD + (long)n * 32 + k] = (_Float16)acc;
}

// ---------------- prep: emit fragment-major Y ----------------
__global__ __launch_bounds__(256)
void prep_frag(const float* __restrict__ Whds, const float* __restrict__ Wfc3,
               _Float16* __restrict__ ws)
{
  const int t = (int)blockIdx.x * 256 + (int)threadIdx.x;
  if (t >= NSLICES * 1024) return;
  const int l = t & 63, q = (t >> 6) & 1, w = (t >> 7) & 7, i = t >> 10;
  const int c  = w * 32 + q * 16 + (l & 15);
  const int kc = l >> 4;
  half8 v;
  if (i < 3) {            // folded enc, X_WE n-major [256][96]
    const _Float16* src = ws + O_WE + (long)c * 96 + i * 32 + kc * 8;
#pragma unroll
    for (int e = 0; e < 8; ++e) v[e] = src[e];
  } else if (i == 3) {    // folded dec, X_WD n-major [256][32]
    const _Float16* src = ws + O_WD + (long)c * 32 + kc * 8;
#pragma unroll
    for (int e = 0; e < 8; ++e) v[e] = src[e];
  } else {                // heads (m<8) / fc3 (m==8), f32 [k][n]
    const int m  = (i - 4) >> 3;
    const int k0 = ((i - 4) & 7) * 32 + kc * 8;
    const float* src = ((m < 8) ? (Whds + ((long)m << 16)) : Wfc3) + (long)k0 * 256 + c;
#pragma unroll
    for (int e = 0; e < 8; ++e) v[e] = (_Float16)src[(long)e * 256];
  }
  *(half8*)&ws[O_Y + (long)i * 8192 + w * 1024 + q * 512 + l * 8] = v;
}

// lgkm-only barrier: LDS visibility; global B prefetches stay in flight
__device__ __forceinline__ void sync_lgkm() {
  asm volatile("s_waitcnt lgkmcnt(0)" ::: "memory");
  __builtin_amdgcn_s_barrier();
}

typedef const __attribute__((address_space(1))) half8* gptr8;

// =========================== main fused kernel ===========================
__global__ __launch_bounds__(NT)
void fused_mfma(const float* __restrict__ x,
                const float* __restrict__ bhds,
                const float* __restrict__ bfc3,
                const float* __restrict__ Wq,  const float* __restrict__ bq,
                const int* __restrict__ agent,
                const _Float16* __restrict__ ws,
                float* __restrict__ out)
{
  __shared__ _Float16 A[ROWS * 256];        // 64 KB
  __shared__ float sp[2][8][ROWS];          // 8 KB

  const int tid  = (int)threadIdx.x;
  const int lane = tid & 63;
  const int wave = tid >> 6;        // 0..15
  const int rg   = wave >> 3;       // 0..1 : 64-row group
  const int wn   = wave & 7;        // 0..7 : 32-col stripe
  const int l15  = lane & 15;
  const int l4   = lane >> 4;
  const int rbase = rg * 64;
  const int cbase = wn * 32;
  const int row0 = (int)blockIdx.x * ROWS;
  const int a = agent[0];

  // fragment-major B: fully-coalesced 1KB wave loads (shared by both row groups)
  const _Float16* myB = ws + O_Y + (long)wn * 1024 + (long)lane * 8;
  auto loadB = [&](int i, half8& qa, half8& qb) {
    const _Float16* p = myB + (long)i * 8192;
    qa = *(gptr8)p;
    qb = *(gptr8)(p + 512);
  };
  auto ldAF = [&](half8 (&af)[4], int acol) {
#pragma unroll
    for (int mt = 0; mt < 4; ++mt) {
      const int row = rbase + mt * 16 + l15;
      const int cch = (acol >> 3) + l4;
      af[mt] = *(const half8*)&A[row * 256 + ((cch ^ (row & 7)) << 3)];
    }
  };
  auto mfma8 = [&](const half8 (&af)[4], const half8& ba, const half8& bb,
                   f32x4 (&acc)[4][2]) {
    __builtin_amdgcn_s_setprio(1);
#pragma unroll
    for (int mt = 0; mt < 4; ++mt) {
      acc[mt][0] = __builtin_amdgcn_mfma_f32_16x16x32_f16(af[mt], ba, acc[mt][0], 0, 0, 0);
      acc[mt][1] = __builtin_amdgcn_mfma_f32_16x16x32_f16(af[mt], bb, acc[mt][1], 0, 0, 0);
    }
    __builtin_amdgcn_s_setprio(0);
  };
  auto zeroAcc = [&](f32x4 (&acc)[4][2]) {
#pragma unroll
    for (int mt = 0; mt < 4; ++mt)
#pragma unroll
      for (int nt = 0; nt < 2; ++nt) acc[mt][nt] = { 0.f, 0.f, 0.f, 0.f };
  };
  auto writeA = [&](const f32x4 (&acc)[4][2], bool relu) {
#pragma unroll
    for (int mt = 0; mt < 4; ++mt)
#pragma unroll
      for (int nt = 0; nt < 2; ++nt)
#pragma unroll
        for (int r = 0; r < 4; ++r) {
          float v = acc[mt][nt][r];
          if (relu) v = fmaxf(v, 0.f);
          A[aidx(rbase + mt * 16 + l4 * 4 + r, cbase + nt * 16 + l15)] = (_Float16)v;
        }
  };

  // merge-tree reduce: 16 values over 16 lanes -> lane l15 holds full sum of
  // value j==l15 (15 shfl instead of 64).
  auto reduce16 = [&](float (&p)[4][4]) -> float {
    float v[16];
#pragma unroll
    for (int mt = 0; mt < 4; ++mt)
#pragma unroll
      for (int r = 0; r < 4; ++r) v[mt * 4 + r] = p[mt][r];
#pragma unroll
    for (int s = 0; s < 4; ++s) {
      const bool hiSel = (l15 >> s) & 1;
#pragma unroll
      for (int j = 0; j < (8 >> s); ++j) {
        const float lo = v[2 * j], hi = v[2 * j + 1];
        const float keep = hiSel ? hi : lo;
        const float send = hiSel ? lo : hi;
        v[j] = keep + __shfl_xor(send, 1 << s, 64);
      }
    }
    return v[0];
  };
  // row (within this wave's row group) of this lane's reduced value
  const int redRow = (l15 >> 2) * 16 + l4 * 4 + (l15 & 3);

  // ---- depth-4 B pipeline prologue ----
  half8 q0a, q0b, q1a, q1b, q2a, q2b, q3a, q3b;
  loadB(0, q0a, q0b); loadB(1, q1a, q1b);
  loadB(2, q2a, q2b); loadB(3, q3a, q3b);

  // ---- build A0 (cols 0..127): enc-in 0..76, 77=1, dec-others 96..105, 106=1 ----
  for (int i = tid; i < ROWS * 128; i += NT) {
    const int r = i >> 7, c = i & 127;
    float v = 0.f;
    const size_t xb = (size_t)(row0 + r) * INW;
    if (c < 72)            v = x[xb + c];
    else if (c < 77)       v = x[xb + 72 + 5 * a + (c - 72)];
    else if (c == 77)      v = 1.f;
    else if (c >= 96 && c < 106) {
      const int o = c - 96;
      v = x[xb + 72 + (o < 5 * a ? o : o + 5)];
    }
    else if (c == 106)     v = 1.f;
    A[aidx(r, c)] = (_Float16)v;
  }
  sync_lgkm();

  // ---- enc_h pre-relu (K=96) ; dec_H pre-relu (K=32) ----
  f32x4 accE[4][2], accD[4][2], acc[4][2];
  zeroAcc(accE); zeroAcc(accD);
  {
    half8 af[4];
    ldAF(af, 0);  mfma8(af, q0a, q0b, accE); loadB(4, q0a, q0b);
    ldAF(af, 32); mfma8(af, q1a, q1b, accE); loadB(5, q1a, q1b);
    ldAF(af, 64); mfma8(af, q2a, q2b, accE); loadB(6, q2a, q2b);
    ldAF(af, 96); mfma8(af, q3a, q3b, accD); loadB(7, q3a, q3b);
  }

  half2v dpk[4][2][2];                // dec_H = relu, packed fp16
#pragma unroll
  for (int mt = 0; mt < 4; ++mt)
#pragma unroll
    for (int nt = 0; nt < 2; ++nt)
#pragma unroll
      for (int rh = 0; rh < 2; ++rh)
        dpk[mt][nt][rh] = half2v{
            (_Float16)fmaxf(accD[mt][nt][2 * rh], 0.f),
            (_Float16)fmaxf(accD[mt][nt][2 * rh + 1], 0.f) };

  sync_lgkm();                        // A0 reads done
  writeA(accE, true);                 // A := enc_h = relu(...)
  sync_lgkm();

  // ---- heads + online softmax; softmax state at row == rbase+lane ----
  f32x4 ctx[4][2];
  zeroAcc(ctx);
  float s0L = 0.f, lsumL = 1.f;

  half8 afC[4], afN[4];
  ldAF(afC, 0);

#pragma unroll
  for (int h = 0; h < 8; ++h) {
    const int base = 4 + 8 * h;
    float bh0 = bhds[h * 256 + cbase + l15];
    float bh1 = bhds[h * 256 + cbase + 16 + l15];

    zeroAcc(acc);
    ldAF(afN, 32);  mfma8(afC, q0a, q0b, acc); loadB(base + 4,  q0a, q0b);
    ldAF(afC, 64);  mfma8(afN, q1a, q1b, acc); loadB(base + 5,  q1a, q1b);
    ldAF(afN, 96);  mfma8(afC, q2a, q2b, acc); loadB(base + 6,  q2a, q2b);
    ldAF(afC, 128); mfma8(afN, q3a, q3b, acc); loadB(base + 7,  q3a, q3b);
    ldAF(afN, 160); mfma8(afC, q0a, q0b, acc); loadB(base + 8,  q0a, q0b);
    ldAF(afC, 192); mfma8(afN, q1a, q1b, acc); loadB(base + 9,  q1a, q1b);
    ldAF(afN, 224); mfma8(afC, q2a, q2b, acc); loadB(base + 10, q2a, q2b);
    ldAF(afC, 0);   mfma8(afN, q3a, q3b, acc); loadB(base + 11, q3a, q3b);

#pragma unroll
    for (int mt = 0; mt < 4; ++mt)
#pragma unroll
      for (int r = 0; r < 4; ++r) {
        acc[mt][0][r] = fmaxf(acc[mt][0][r] + bh0, 0.f);
        acc[mt][1][r] = fmaxf(acc[mt][1][r] + bh1, 0.f);
      }

    // score partials over this wave's 32 cols, merge-tree reduce, 1 write/lane
    float p[4][4];
#pragma unroll
    for (int mt = 0; mt < 4; ++mt)
#pragma unroll
      for (int r = 0; r < 4; ++r) {
        float v = 0.f;
#pragma unroll
        for (int nt = 0; nt < 2; ++nt)
          v = fmaf(acc[mt][nt][r], (float)dpk[mt][nt][r >> 1][r & 1], v);
        p[mt][r] = v;
      }
    sp[h & 1][wn][rbase + redRow] = reduce16(p);
    sync_lgkm();                      // sp[h&1] visible; B loads stay in flight

    // total score for row == rbase+lane (8 scalar LDS reads), softmax update
    float sh = 0.f;
#pragma unroll
    for (int w = 0; w < 8; ++w) sh += sp[h & 1][w][rbase + lane];
    float wL;
    if (h == 0) { s0L = sh; lsumL = 1.f; wL = 1.f; }
    else        { wL = __expf(fminf(sh - s0L, 70.f)); lsumL += wL; }

    // redistribute weight to the (mt,r) holders of each row
#pragma unroll
    for (int mt = 0; mt < 4; ++mt)
#pragma unroll
      for (int r = 0; r < 4; ++r) {
        const float wgt = __shfl(wL, mt * 16 + l4 * 4 + r, 64);
#pragma unroll
        for (int nt = 0; nt < 2; ++nt)
          ctx[mt][nt][r] = fmaf(wgt, acc[mt][nt][r], ctx[mt][nt][r]);
      }
    // sp[h&1] reused at h+2; fenced by head h+1's barrier
  }

  // normalize context (inv at row==rbase+lane, shfl out)
  {
    const float invL = 1.f / lsumL;
#pragma unroll
    for (int mt = 0; mt < 4; ++mt)
#pragma unroll
      for (int r = 0; r < 4; ++r) {
        const float inv = __shfl(invL, mt * 16 + l4 * 4 + r, 64);
#pragma unroll
        for (int nt = 0; nt < 2; ++nt) ctx[mt][nt][r] *= inv;
      }
  }
  sync_lgkm();                        // head-7 A reads done
  writeA(ctx, false);                 // A := context
  sync_lgkm();

  // ---- fc3 (+bias+relu) then @ Wq ----
  float bf30 = bfc3[cbase + l15],      bf31 = bfc3[cbase + 16 + l15];
  float wq0  = Wq[cbase + l15],        wq1  = Wq[cbase + 16 + l15];

  zeroAcc(acc);
  ldAF(afC, 0);
  // entering: q0..q3 = slices 68..71 (loaded during head 7)
  ldAF(afN, 32);  mfma8(afC, q0a, q0b, acc); loadB(72, q0a, q0b);
  ldAF(afC, 64);  mfma8(afN, q1a, q1b, acc); loadB(73, q1a, q1b);
  ldAF(afN, 96);  mfma8(afC, q2a, q2b, acc); loadB(74, q2a, q2b);
  ldAF(afC, 128); mfma8(afN, q3a, q3b, acc); loadB(75, q3a, q3b);
  ldAF(afN, 160); mfma8(afC, q0a, q0b, acc);
  ldAF(afC, 192); mfma8(afN, q1a, q1b, acc);
  ldAF(afN, 224); mfma8(afC, q2a, q2b, acc);
                  mfma8(afN, q3a, q3b, acc);

  float p[4][4];
#pragma unroll
  for (int mt = 0; mt < 4; ++mt)
#pragma unroll
    for (int r = 0; r < 4; ++r) {
      p[mt][r] = fmaf(fmaxf(acc[mt][0][r] + bf30, 0.f), wq0,
                      fmaxf(acc[mt][1][r] + bf31, 0.f) * wq1);
    }
  sp[0][wn][rbase + redRow] = reduce16(p);
  sync_lgkm();
  if (tid < ROWS) {
    float v = bq[0];
#pragma unroll
    for (int w = 0; w < 8; ++w) v += sp[0][w][tid];
    out[row0 + tid] = v;
  }
}

}  // namespace

extern "C" void kernel_launch(void* const* d_in, const int* in_sizes, int n_in,
                              void* d_out, int out_size, void* d_ws, size_t ws_size,
                              hipStream_t stream) {
  const float* x    = (const float*)d_in[0];
  const float* Wfc1 = (const float*)d_in[1];
  const float* bfc1 = (const float*)d_in[2];
  const float* Wfc2 = (const float*)d_in[3];
  const float* bfc2 = (const float*)d_in[4];
  const float* Wenc = (const float*)d_in[5];
  const float* benc = (const float*)d_in[6];
  const float* Whds = (const float*)d_in[7];
  const float* bhds = (const float*)d_in[8];
  const float* Wdec = (const float*)d_in[9];
  const float* bdec = (const float*)d_in[10];
  const float* Wfc3 = (const float*)d_in[11];
  const float* bfc3 = (const float*)d_in[12];
  const float* Wq   = (const float*)d_in[13];
  const float* bq   = (const float*)d_in[14];
  const int*  agent = (const int*)d_in[15];
  float* out = (float*)d_out;
  _Float16* ws = (_Float16*)d_ws;

  const int Bn = in_sizes[0] / INW;         // 32768
  const int grid = Bn / ROWS;               // 256 blocks = 1/CU, one round

  prep_fold_enc<<<96, 256, 0, stream>>>(Wfc1, bfc1, Wenc, benc, ws);
  prep_fold_dec<<<32, 256, 0, stream>>>(Wfc2, bfc2, Wdec, bdec, ws);
  prep_frag<<<(NSLICES * 1024 + 255) / 256, 256, 0, stream>>>(Whds, Wfc3, ws);
  fused_mfma<<<grid, NT, 0, stream>>>(x, bhds, bfc3, Wq, bq, agent, ws, out);
}

// Round 24
// 73.661 us; speedup vs baseline: 2.4859x; 2.4859x over previous
//
#include <hip/hip_runtime.h>
#include <hip/hip_bf16.h>

typedef _Float16 half8 __attribute__((ext_vector_type(8)));
typedef _Float16 half4 __attribute__((ext_vector_type(4)));
typedef _Float16 half2v __attribute__((ext_vector_type(2)));
typedef float f32x4 __attribute__((ext_vector_type(4)));

namespace {

constexpr int INW  = 87;
constexpr int ROWS = 64;    // rows per block
constexpr int NT   = 512;   // 8 waves, each owns a 32-col stripe, all 64 rows
constexpr int NSLICES = 76; // 3(WE) + 1(WD) + 64(heads) + 8(fc3)

// ws halves layout:
//   X_WE  [256][96]  n-major folded enc (k<77 real, k==77 bias row)
//   X_WD  [256][32]  n-major folded dec (k<10 real, k==10 bias row)
//   Y     fragment-major: slice i (76) x stripe w (8) x {qa,qb} x lane(64) x 8 halves
constexpr long O_WE = 0;        // 24576 halves
constexpr long O_WD = 24576;    // 8192 halves
constexpr long O_Y  = 32768;    // 76*8192 = 622592 halves

__device__ __forceinline__ int aidx(int row, int col) {
  return row * 256 + ((((col >> 3) ^ (row & 7)) << 3) | (col & 7));
}

// ---------------- prep: fold enc chain -> X_WE ----------------
__global__ __launch_bounds__(256)
void prep_fold_enc(const float* __restrict__ Wfc1, const float* __restrict__ bfc1,
                   const float* __restrict__ Wenc, const float* __restrict__ benc,
                   _Float16* __restrict__ ws)
{
  const int t = (int)blockIdx.x * 256 + (int)threadIdx.x;   // 96*256 threads
  const int n = t & 255, k = t >> 8;                        // k 0..95
  float acc = 0.f;
  if (k < 77) {
    for (int m = 0; m < 256; ++m) acc += Wfc1[(size_t)k * 256 + m] * Wenc[(size_t)m * 256 + n];
  } else if (k == 77) {
    for (int m = 0; m < 256; ++m) acc += bfc1[m] * Wenc[(size_t)m * 256 + n];
    acc += benc[n];
  }
  ws[O_WE + (long)n * 96 + k] = (_Float16)acc;
}

// ---------------- prep: fold dec chain -> X_WD ----------------
__global__ __launch_bounds__(256)
void prep_fold_dec(const float* __restrict__ Wfc2, const float* __restrict__ bfc2,
                   const float* __restrict__ Wdec, const float* __restrict__ bdec,
                   _Float16* __restrict__ ws)
{
  const int t = (int)blockIdx.x * 256 + (int)threadIdx.x;   // 32*256 threads
  const int n = t & 255, k = t >> 8;                        // k 0..31
  float acc = 0.f;
  if (k < 10) {
    for (int m = 0; m < 256; ++m) acc += Wfc2[(size_t)k * 256 + m] * Wdec[(size_t)m * 256 + n];
  } else if (k == 10) {
    for (int m = 0; m < 256; ++m) acc += bfc2[m] * Wdec[(size_t)m * 256 + n];
    acc += bdec[n];
  }
  ws[O_WD + (long)n * 32 + k] = (_Float16)acc;
}

// ---------------- prep: emit fragment-major Y ----------------
__global__ __launch_bounds__(256)
void prep_frag(const float* __restrict__ Whds, const float* __restrict__ Wfc3,
               _Float16* __restrict__ ws)
{
  const int t = (int)blockIdx.x * 256 + (int)threadIdx.x;
  if (t >= NSLICES * 1024) return;
  const int l = t & 63, q = (t >> 6) & 1, w = (t >> 7) & 7, i = t >> 10;
  const int c  = w * 32 + q * 16 + (l & 15);
  const int kc = l >> 4;
  half8 v;
  if (i < 3) {            // folded enc, X_WE n-major [256][96]
    const _Float16* src = ws + O_WE + (long)c * 96 + i * 32 + kc * 8;
#pragma unroll
    for (int e = 0; e < 8; ++e) v[e] = src[e];
  } else if (i == 3) {    // folded dec, X_WD n-major [256][32]
    const _Float16* src = ws + O_WD + (long)c * 32 + kc * 8;
#pragma unroll
    for (int e = 0; e < 8; ++e) v[e] = src[e];
  } else {                // heads (m<8) / fc3 (m==8), f32 [k][n]
    const int m  = (i - 4) >> 3;
    const int k0 = ((i - 4) & 7) * 32 + kc * 8;
    const float* src = ((m < 8) ? (Whds + ((long)m << 16)) : Wfc3) + (long)k0 * 256 + c;
#pragma unroll
    for (int e = 0; e < 8; ++e) v[e] = (_Float16)src[(long)e * 256];
  }
  *(half8*)&ws[O_Y + (long)i * 8192 + w * 1024 + q * 512 + l * 8] = v;
}

// lgkm-only barrier: LDS visibility; global B prefetches stay in flight
__device__ __forceinline__ void sync_lgkm() {
  asm volatile("s_waitcnt lgkmcnt(0)" ::: "memory");
  __builtin_amdgcn_s_barrier();
}

typedef const __attribute__((address_space(1))) half8* gptr8;

// =========================== main fused kernel ===========================
__global__ __launch_bounds__(NT)
void fused_mfma(const float* __restrict__ x,
                const float* __restrict__ bhds,
                const float* __restrict__ bfc3,
                const float* __restrict__ Wq,  const float* __restrict__ bq,
                const int* __restrict__ agent,
                const _Float16* __restrict__ ws,
                float* __restrict__ out)
{
  __shared__ _Float16 A[ROWS * 256];        // 32 KB
  __shared__ float sp[2][8][ROWS];          // 4 KB

  const int tid  = (int)threadIdx.x;
  const int lane = tid & 63;
  const int wn   = tid >> 6;        // 0..7 : this wave's 32-col stripe
  const int l15  = lane & 15;
  const int l4   = lane >> 4;
  const int cbase = wn * 32;
  const int row0 = (int)blockIdx.x * ROWS;
  const int a = agent[0];

  // fragment-major B: fully-coalesced 1KB wave loads
  const _Float16* myB = ws + O_Y + (long)wn * 1024 + (long)lane * 8;
  auto loadB = [&](int i, half8& qa, half8& qb) {
    const _Float16* p = myB + (long)i * 8192;
    qa = *(gptr8)p;
    qb = *(gptr8)(p + 512);
  };
  auto ldAF = [&](half8 (&af)[4], int acol) {
#pragma unroll
    for (int mt = 0; mt < 4; ++mt) {
      const int row = mt * 16 + l15;
      const int cch = (acol >> 3) + l4;
      af[mt] = *(const half8*)&A[row * 256 + ((cch ^ (row & 7)) << 3)];
    }
  };
  auto mfma8 = [&](const half8 (&af)[4], const half8& ba, const half8& bb,
                   f32x4 (&acc)[4][2]) {
    __builtin_amdgcn_s_setprio(1);
#pragma unroll
    for (int mt = 0; mt < 4; ++mt) {
      acc[mt][0] = __builtin_amdgcn_mfma_f32_16x16x32_f16(af[mt], ba, acc[mt][0], 0, 0, 0);
      acc[mt][1] = __builtin_amdgcn_mfma_f32_16x16x32_f16(af[mt], bb, acc[mt][1], 0, 0, 0);
    }
    __builtin_amdgcn_s_setprio(0);
  };
  auto zeroAcc = [&](f32x4 (&acc)[4][2]) {
#pragma unroll
    for (int mt = 0; mt < 4; ++mt)
#pragma unroll
      for (int nt = 0; nt < 2; ++nt) acc[mt][nt] = { 0.f, 0.f, 0.f, 0.f };
  };
  auto writeA = [&](const f32x4 (&acc)[4][2], bool relu) {
#pragma unroll
    for (int mt = 0; mt < 4; ++mt)
#pragma unroll
      for (int nt = 0; nt < 2; ++nt)
#pragma unroll
        for (int r = 0; r < 4; ++r) {
          float v = acc[mt][nt][r];
          if (relu) v = fmaxf(v, 0.f);
          A[aidx(mt * 16 + l4 * 4 + r, cbase + nt * 16 + l15)] = (_Float16)v;
        }
  };

  // merge-tree reduce: 16 values over 16 lanes -> lane l15 holds full sum of
  // value j==l15 (15 shfl instead of 64).
  auto reduce16 = [&](float (&p)[4][4]) -> float {
    float v[16];
#pragma unroll
    for (int mt = 0; mt < 4; ++mt)
#pragma unroll
      for (int r = 0; r < 4; ++r) v[mt * 4 + r] = p[mt][r];
#pragma unroll
    for (int s = 0; s < 4; ++s) {
      const bool hiSel = (l15 >> s) & 1;
#pragma unroll
      for (int j = 0; j < (8 >> s); ++j) {
        const float lo = v[2 * j], hi = v[2 * j + 1];
        const float keep = hiSel ? hi : lo;
        const float send = hiSel ? lo : hi;
        v[j] = keep + __shfl_xor(send, 1 << s, 64);
      }
    }
    return v[0];
  };
  // row this lane's reduced value belongs to (j == l15)
  const int redRow = (l15 >> 2) * 16 + l4 * 4 + (l15 & 3);

  // ---- depth-4 B pipeline prologue ----
  half8 q0a, q0b, q1a, q1b, q2a, q2b, q3a, q3b;
  loadB(0, q0a, q0b); loadB(1, q1a, q1b);
  loadB(2, q2a, q2b); loadB(3, q3a, q3b);

  // ---- build A0 (cols 0..127): enc-in 0..76, 77=1, dec-others 96..105, 106=1 ----
  for (int i = tid; i < ROWS * 128; i += NT) {
    const int r = i >> 7, c = i & 127;
    float v = 0.f;
    const size_t xb = (size_t)(row0 + r) * INW;
    if (c < 72)            v = x[xb + c];
    else if (c < 77)       v = x[xb + 72 + 5 * a + (c - 72)];
    else if (c == 77)      v = 1.f;
    else if (c >= 96 && c < 106) {
      const int o = c - 96;
      v = x[xb + 72 + (o < 5 * a ? o : o + 5)];
    }
    else if (c == 106)     v = 1.f;
    A[aidx(r, c)] = (_Float16)v;
  }
  sync_lgkm();

  // ---- enc_h pre-relu (K=96) ; dec_H pre-relu (K=32) ----
  f32x4 accE[4][2], accD[4][2], acc[4][2];
  zeroAcc(accE); zeroAcc(accD);
  {
    half8 af[4];
    ldAF(af, 0);  mfma8(af, q0a, q0b, accE); loadB(4, q0a, q0b);
    ldAF(af, 32); mfma8(af, q1a, q1b, accE); loadB(5, q1a, q1b);
    ldAF(af, 64); mfma8(af, q2a, q2b, accE); loadB(6, q2a, q2b);
    ldAF(af, 96); mfma8(af, q3a, q3b, accD); loadB(7, q3a, q3b);
  }

  half2v dpk[4][2][2];                // dec_H = relu, packed fp16
#pragma unroll
  for (int mt = 0; mt < 4; ++mt)
#pragma unroll
    for (int nt = 0; nt < 2; ++nt)
#pragma unroll
      for (int rh = 0; rh < 2; ++rh)
        dpk[mt][nt][rh] = half2v{
            (_Float16)fmaxf(accD[mt][nt][2 * rh], 0.f),
            (_Float16)fmaxf(accD[mt][nt][2 * rh + 1], 0.f) };

  sync_lgkm();                        // A0 reads done
  writeA(accE, true);                 // A := enc_h = relu(...)
  sync_lgkm();

  // ---- heads + online softmax; softmax state lives at row==lane ----
  f32x4 ctx[4][2];
  zeroAcc(ctx);
  float s0L = 0.f, lsumL = 1.f;       // for row == lane

  half8 afC[4], afN[4];
  ldAF(afC, 0);

#pragma unroll
  for (int h = 0; h < 8; ++h) {
    const int base = 4 + 8 * h;
    float bh0 = bhds[h * 256 + cbase + l15];
    float bh1 = bhds[h * 256 + cbase + 16 + l15];

    zeroAcc(acc);
    ldAF(afN, 32);  mfma8(afC, q0a, q0b, acc); loadB(base + 4,  q0a, q0b);
    ldAF(afC, 64);  mfma8(afN, q1a, q1b, acc); loadB(base + 5,  q1a, q1b);
    ldAF(afN, 96);  mfma8(afC, q2a, q2b, acc); loadB(base + 6,  q2a, q2b);
    ldAF(afC, 128); mfma8(afN, q3a, q3b, acc); loadB(base + 7,  q3a, q3b);
    ldAF(afN, 160); mfma8(afC, q0a, q0b, acc); loadB(base + 8,  q0a, q0b);
    ldAF(afC, 192); mfma8(afN, q1a, q1b, acc); loadB(base + 9,  q1a, q1b);
    ldAF(afN, 224); mfma8(afC, q2a, q2b, acc); loadB(base + 10, q2a, q2b);
    ldAF(afC, 0);   mfma8(afN, q3a, q3b, acc); loadB(base + 11, q3a, q3b);

#pragma unroll
    for (int mt = 0; mt < 4; ++mt)
#pragma unroll
      for (int r = 0; r < 4; ++r) {
        acc[mt][0][r] = fmaxf(acc[mt][0][r] + bh0, 0.f);
        acc[mt][1][r] = fmaxf(acc[mt][1][r] + bh1, 0.f);
      }

    // score partials over this wave's 32 cols, merge-tree reduce, 1 write/lane
    float p[4][4];
#pragma unroll
    for (int mt = 0; mt < 4; ++mt)
#pragma unroll
      for (int r = 0; r < 4; ++r) {
        float v = 0.f;
#pragma unroll
        for (int nt = 0; nt < 2; ++nt)
          v = fmaf(acc[mt][nt][r], (float)dpk[mt][nt][r >> 1][r & 1], v);
        p[mt][r] = v;
      }
    sp[h & 1][wn][redRow] = reduce16(p);
    sync_lgkm();                      // sp[h&1] visible; B loads stay in flight

    // total score for row == lane (8 scalar LDS reads), softmax update
    float sh = 0.f;
#pragma unroll
    for (int w = 0; w < 8; ++w) sh += sp[h & 1][w][lane];
    float wL;
    if (h == 0) { s0L = sh; lsumL = 1.f; wL = 1.f; }
    else        { wL = __expf(fminf(sh - s0L, 70.f)); lsumL += wL; }

    // redistribute weight to the (mt,r) holders of each row
#pragma unroll
    for (int mt = 0; mt < 4; ++mt)
#pragma unroll
      for (int r = 0; r < 4; ++r) {
        const float wgt = __shfl(wL, mt * 16 + l4 * 4 + r, 64);
#pragma unroll
        for (int nt = 0; nt < 2; ++nt)
          ctx[mt][nt][r] = fmaf(wgt, acc[mt][nt][r], ctx[mt][nt][r]);
      }
    // sp[h&1] reused at h+2; fenced by head h+1's barrier
  }

  // normalize context (inv at row==lane, shfl out)
  {
    const float invL = 1.f / lsumL;
#pragma unroll
    for (int mt = 0; mt < 4; ++mt)
#pragma unroll
      for (int r = 0; r < 4; ++r) {
        const float inv = __shfl(invL, mt * 16 + l4 * 4 + r, 64);
#pragma unroll
        for (int nt = 0; nt < 2; ++nt) ctx[mt][nt][r] *= inv;
      }
  }
  sync_lgkm();                        // head-7 A reads done
  writeA(ctx, false);                 // A := context
  sync_lgkm();

  // ---- fc3 (+bias+relu) then @ Wq ----
  float bf30 = bfc3[cbase + l15],      bf31 = bfc3[cbase + 16 + l15];
  float wq0  = Wq[cbase + l15],        wq1  = Wq[cbase + 16 + l15];

  zeroAcc(acc);
  ldAF(afC, 0);
  // entering: q0..q3 = slices 68..71 (loaded during head 7)
  ldAF(afN, 32);  mfma8(afC, q0a, q0b, acc); loadB(72, q0a, q0b);
  ldAF(afC, 64);  mfma8(afN, q1a, q1b, acc); loadB(73, q1a, q1b);
  ldAF(afN, 96);  mfma8(afC, q2a, q2b, acc); loadB(74, q2a, q2b);
  ldAF(afC, 128); mfma8(afN, q3a, q3b, acc); loadB(75, q3a, q3b);
  ldAF(afN, 160); mfma8(afC, q0a, q0b, acc);
  ldAF(afC, 192); mfma8(afN, q1a, q1b, acc);
  ldAF(afN, 224); mfma8(afC, q2a, q2b, acc);
                  mfma8(afN, q3a, q3b, acc);

  float p[4][4];
#pragma unroll
  for (int mt = 0; mt < 4; ++mt)
#pragma unroll
    for (int r = 0; r < 4; ++r) {
      p[mt][r] = fmaf(fmaxf(acc[mt][0][r] + bf30, 0.f), wq0,
                      fmaxf(acc[mt][1][r] + bf31, 0.f) * wq1);
    }
  sp[0][wn][redRow] = reduce16(p);
  sync_lgkm();
  if (tid < ROWS) {
    float v = bq[0];
#pragma unroll
    for (int w = 0; w < 8; ++w) v += sp[0][w][tid];
    out[row0 + tid] = v;
  }
}

}  // namespace

extern "C" void kernel_launch(void* const* d_in, const int* in_sizes, int n_in,
                              void* d_out, int out_size, void* d_ws, size_t ws_size,
                              hipStream_t stream) {
  const float* x    = (const float*)d_in[0];
  const float* Wfc1 = (const float*)d_in[1];
  const float* bfc1 = (const float*)d_in[2];
  const float* Wfc2 = (const float*)d_in[3];
  const float* bfc2 = (const float*)d_in[4];
  const float* Wenc = (const float*)d_in[5];
  const float* benc = (const float*)d_in[6];
  const float* Whds = (const float*)d_in[7];
  const float* bhds = (const float*)d_in[8];
  const float* Wdec = (const float*)d_in[9];
  const float* bdec = (const float*)d_in[10];
  const float* Wfc3 = (const float*)d_in[11];
  const float* bfc3 = (const float*)d_in[12];
  const float* Wq   = (const float*)d_in[13];
  const float* bq   = (const float*)d_in[14];
  const int*  agent = (const int*)d_in[15];
  float* out = (float*)d_out;
  _Float16* ws = (_Float16*)d_ws;

  const int Bn = in_sizes[0] / INW;         // 32768
  const int grid = Bn / ROWS;               // 512 blocks

  prep_fold_enc<<<96, 256, 0, stream>>>(Wfc1, bfc1, Wenc, benc, ws);
  prep_fold_dec<<<32, 256, 0, stream>>>(Wfc2, bfc2, Wdec, bdec, ws);
  prep_frag<<<(NSLICES * 1024 + 255) / 256, 256, 0, stream>>>(Whds, Wfc3, ws);
  fused_mfma<<<grid, NT, 0, stream>>>(x, bhds, bfc3, Wq, bq, agent, ws, out);
}